// Round 12
// baseline (250.156 us; speedup 1.0000x reference)
//
#include <hip/hip_runtime.h>
#include <stdint.h>

#define GRAPHS 256
#define NPG    512
#define EPG    8192
#define NTOT   (GRAPHS*NPG)

typedef __attribute__((ext_vector_type(8))) short s16x8;
typedef __attribute__((ext_vector_type(4))) float f32x4;

__device__ __forceinline__ float bf2f(unsigned short u){
  union { unsigned int i; float f; } c; c.i = ((unsigned int)u)<<16; return c.f;
}
__device__ __forceinline__ unsigned short f2bf(float f){
  union { float f; unsigned int i; } c; c.f = f;
  unsigned int r = c.i + 0x7fffu + ((c.i>>16)&1u);   // RNE
  return (unsigned short)(r>>16);
}

// ---------- CSR build + out_isqrt (blocks 0..255) ; EW1T prep (256..271) ----
__global__ __launch_bounds__(512) void k_csr(const int* __restrict__ src,
      const int* __restrict__ dst, const int* __restrict__ ntype,
      const float* __restrict__ emb, const float* __restrict__ W1,
      unsigned short* __restrict__ sorted_g, int* __restrict__ start_g,
      float* __restrict__ out_isqrt, unsigned short* __restrict__ EW1T){
  __shared__ int hist[NPG], cursor[NPG], co[NPG], cs[NPG+1];
  __shared__ unsigned short ntype_sh[NPG];
  __shared__ unsigned short sorted[EPG];
  const int tid=threadIdx.x;
  if (blockIdx.x >= GRAPHS){                     // fused EW1T = (emb@W1)^T
    const int gid = (blockIdx.x-GRAPHS)*512 + tid;   // 16 blocks * 512 = 8192
    const int t = gid>>7, c = gid&127;
    float acc=0.f;
    #pragma unroll 4
    for (int k=0;k<128;k++) acc += emb[t*128+k]*W1[k*128+c];
    EW1T[c*64+t]=f2bf(acc);
    return;
  }
  const int b=blockIdx.x, eb=b*EPG, nb=b*NPG;
  for (int v=tid; v<NPG; v+=512){
    hist[v]=0; co[v]=0; ntype_sh[v]=(unsigned short)ntype[nb+v];
  }
  __syncthreads();
  for (int i=tid;i<EPG;i+=512){
    atomicAdd(&hist[dst[eb+i]&(NPG-1)],1);
    atomicAdd(&co[src[eb+i]&(NPG-1)],1);
  }
  __syncthreads();
  if (tid<64){
    int carry=0;
    #pragma unroll
    for (int c=0;c<8;c++){
      int sc=hist[64*c+tid];
      #pragma unroll
      for (int off=1;off<64;off<<=1){ int y=__shfl_up(sc,off); if (tid>=off) sc+=y; }
      cs[64*c+tid+1]=carry+sc;
      carry+=__shfl(sc,63);
    }
    if (tid==0) cs[0]=0;
  }
  __syncthreads();
  for (int v=tid;v<NPG;v+=512) cursor[v]=cs[v];
  __syncthreads();
  for (int i=tid;i<EPG;i+=512){
    const int s=src[eb+i]&(NPG-1), d=dst[eb+i]&(NPG-1);
    const int pos=atomicAdd(&cursor[d],1);
    sorted[pos]=(unsigned short)((ntype_sh[s]<<9)|s);
  }
  __syncthreads();
  for (int i=tid;i<EPG/2;i+=512)
    ((unsigned int*)(sorted_g+(size_t)eb))[i] = ((const unsigned int*)sorted)[i];
  for (int v=tid;v<=NPG;v+=512) start_g[b*(NPG+1)+v]=cs[v];
  for (int v=tid;v<NPG;v+=512){
    int a=co[v]; if(a<1)a=1;
    out_isqrt[nb+v]=rsqrtf((float)a);
  }
}

// ---------- layer-1: S-histogram + MFMA(S_hi/lo @ EW1) ----------------------
// block = (graph, half: 256 dst rows), 512 thr (R7/R10-proven config).
// h1T[b*128+col][row] = relu(agg*in_isqrt + b1) * out_isqrt  (bf16)
#define A1_LDS 73232   // S f32[256][68] | wsc[512] | sstart[257] | bsh[128]
__global__ __launch_bounds__(512) void k_agg1(
      const unsigned short* __restrict__ sorted_g, const int* __restrict__ start_g,
      const unsigned short* __restrict__ EW1T, const float* __restrict__ out_isqrt,
      const float* __restrict__ b1, unsigned short* __restrict__ h1T){
  extern __shared__ char smem[];
  float* S      = (float*)(smem);               // [256][68]
  float* wsc    = (float*)(smem + 69632);       // [512]
  int*   sstart = (int*)  (smem + 71680);       // [257]
  float* bsh    = (float*)(smem + 72720);       // [128]
  const int bid=blockIdx.x, b=bid>>1, half=bid&1;
  const int v0=half*256, nb=b*NPG, tid=threadIdx.x;
  for (int i=tid; i<(256*68)/4; i+=512) ((f32x4*)S)[i]=(f32x4){0.f,0.f,0.f,0.f};
  for (int i=tid; i<NPG; i+=512) wsc[i]=out_isqrt[nb+i];
  for (int i=tid; i<257; i+=512) sstart[i]=start_g[b*(NPG+1)+v0+i];
  if (tid<128) bsh[tid]=b1[tid];
  __syncthreads();
  if (tid<256){                                 // thread-per-dst scatter
    const int beg=sstart[tid], end=sstart[tid+1];
    float* Sd = S + tid*68;
    const unsigned short* sg = sorted_g + (size_t)b*EPG;
    for (int i=beg;i<end;++i){
      const int ent = sg[i];
      Sd[ent>>9] += wsc[ent&511];
    }
  }
  __syncthreads();
  const int wave=tid>>6, lane=tid&63, l16=lane&15, quad=lane>>4;
  f32x4 acc[2][8];
  #pragma unroll
  for (int rt=0;rt<2;rt++)
    #pragma unroll
    for (int nt=0;nt<8;nt++) acc[rt][nt]=(f32x4){0.f,0.f,0.f,0.f};
  #pragma unroll
  for (int ks=0; ks<4; ++ks){                   // ks 0,1 = hi; 2,3 = lo
    const int kc = (ks&1)*32 + quad*8;
    s16x8 a[2];
    #pragma unroll
    for (int rt=0;rt<2;rt++){
      const int m = (wave*2+rt)*16 + l16;
      const float* sp = &S[m*68 + kc];
      f32x4 va = *(const f32x4*)sp;
      f32x4 vb = *(const f32x4*)(sp+4);
      union { s16x8 v; unsigned short u[8]; } pk;
      #pragma unroll
      for (int j=0;j<8;j++){
        const float f = (j<4)? va[j] : vb[j-4];
        const unsigned short hi = f2bf(f);
        pk.u[j] = (ks<2) ? hi : f2bf(f - bf2f(hi));
      }
      a[rt]=pk.v;
    }
    #pragma unroll
    for (int nt=0;nt<8;nt++){
      s16x8 bfr=__builtin_bit_cast(s16x8,
          *(const uint4*)(EW1T + (size_t)(nt*16+l16)*64 + kc));
      #pragma unroll
      for (int rt=0;rt<2;rt++)
        acc[rt][nt]=__builtin_amdgcn_mfma_f32_16x16x32_bf16(a[rt],bfr,acc[rt][nt],0,0,0);
    }
  }
  #pragma unroll
  for (int rt=0;rt<2;rt++){
    const int mloc = (wave*2+rt)*16 + quad*4;
    float isq[4], os[4];
    #pragma unroll
    for (int r=0;r<4;r++){
      int d = sstart[mloc+r+1]-sstart[mloc+r]; if (d<1) d=1;
      isq[r]=rsqrtf((float)d);
      os[r]=wsc[v0+mloc+r];
    }
    #pragma unroll
    for (int nt=0;nt<8;nt++){
      const int col = nt*16+l16;
      const float bb = bsh[col];
      ushort4 st;
      float v;
      v = fmaxf(acc[rt][nt][0]*isq[0]+bb,0.f)*os[0]; st.x=f2bf(v);
      v = fmaxf(acc[rt][nt][1]*isq[1]+bb,0.f)*os[1]; st.y=f2bf(v);
      v = fmaxf(acc[rt][nt][2]*isq[2]+bb,0.f)*os[2]; st.z=f2bf(v);
      v = fmaxf(acc[rt][nt][3]*isq[3]+bb,0.f)*os[3]; st.w=f2bf(v);
      *(ushort4*)(h1T + ((size_t)(b*128+col))*512 + v0 + mloc) = st;
    }
  }
}

// ---------- layer-2: A(u8 counts) @ h1T via MFMA -> M1 ----------------------
// block = (graph, 64-dst tile), 512 thr, 33.8 KB LDS -> 4 blocks/CU = 32 waves.
// Occupancy gained structurally (smaller tile), not via VGPR caps (R9 lesson).
// Scatter: CSR slice, 8 threads/dst (~2-edge chains). XCD swizzle: a graph's
// 8 tiles share bid%8 -> same XCD L2 for the h1T slice.
#define A2_LDS 33872   // A u8[64][520]=33280 | sstart[65]
__global__ __launch_bounds__(512) void k_agg2(
      const unsigned short* __restrict__ sorted_g, const int* __restrict__ start_g,
      const unsigned short* __restrict__ h1T, unsigned short* __restrict__ M1){
  extern __shared__ char smem[];
  unsigned char* A = (unsigned char*)smem;      // [64][520]
  unsigned int* A32 = (unsigned int*)smem;
  int* sstart = (int*)(smem + 33280);           // [65]
  const int bid=blockIdx.x;                     // 2048 = 32 * 8dt * 8
  const int b  = ((bid>>6)<<3) | (bid&7);       // graph (XCD swizzle)
  const int dt = (bid>>3)&7;                    // 64-dst tile
  const int v0=dt*64, nb=b*NPG, tid=threadIdx.x;
  for (int i=tid; i<33280/16; i+=512) ((uint4*)smem)[i]=(uint4){0u,0u,0u,0u};
  if (tid<65) sstart[tid]=start_g[b*(NPG+1)+v0+tid];
  __syncthreads();
  {                                             // scatter: 8 threads per dst
    const int d = tid>>3, q = tid&7;
    const int beg=sstart[d], end=sstart[d+1], len=end-beg;
    const int qb = beg + ((len*q)>>3), qe = beg + ((len*(q+1))>>3);
    const unsigned short* sg = sorted_g + (size_t)b*EPG;
    const int rowbase = d*130;
    for (int i=qb;i<qe;++i){
      const int s = sg[i]&511;
      atomicAdd(&A32[rowbase + (s>>2)], 1u<<((s&3)*8));
    }
  }
  __syncthreads();
  const int wave=tid>>6, lane=tid&63, l16=lane&15, quad=lane>>4;
  const int mg=wave>>1, ng=wave&1;              // 4 m-tiles x 2 n-groups
  f32x4 acc[4];
  #pragma unroll
  for (int ct=0;ct<4;ct++) acc[ct]=(f32x4){0.f,0.f,0.f,0.f};
  const unsigned short* hp[4];
  #pragma unroll
  for (int ct=0;ct<4;ct++)
    hp[ct] = h1T + ((size_t)(b*128 + ng*64 + ct*16 + l16))*512 + quad*8;
  const unsigned char* Ab = A + (mg*16 + l16)*520 + quad*8;
  #pragma unroll 2
  for (int ks=0; ks<16; ++ks){
    const uint2 aw = *(const uint2*)(Ab + ks*32);
    union { s16x8 v; unsigned short u[8]; } pk;
    #pragma unroll
    for (int j=0;j<4;j++){
      const float f0 = (float)((aw.x>>(8*j))&0xffu);   // exact small ints
      const float f1 = (float)((aw.y>>(8*j))&0xffu);
      pk.u[j]   = (unsigned short)(__builtin_bit_cast(unsigned int, f0)>>16);
      pk.u[j+4] = (unsigned short)(__builtin_bit_cast(unsigned int, f1)>>16);
    }
    #pragma unroll
    for (int ct=0;ct<4;ct++){
      s16x8 bfr=__builtin_bit_cast(s16x8, *(const uint4*)(hp[ct] + ks*32));
      acc[ct]=__builtin_amdgcn_mfma_f32_16x16x32_bf16(pk.v,bfr,acc[ct],0,0,0);
    }
  }
  const int mloc=mg*16 + quad*4;
  float isq[4];
  #pragma unroll
  for (int r=0;r<4;r++){
    int d=sstart[mloc+r+1]-sstart[mloc+r]; if (d<1) d=1;
    isq[r]=rsqrtf((float)d);
  }
  #pragma unroll
  for (int ct=0;ct<4;ct++){
    const int col=ng*64 + ct*16 + l16;
    #pragma unroll
    for (int r=0;r<4;r++)
      M1[(size_t)(nb+v0+mloc+r)*128 + col] = f2bf(acc[ct][r]*isq[r]);
  }
}

// ---------- final GEMM: relu(M1 @ W2 + b2), fused per-graph mean -> out -----
__global__ __launch_bounds__(512) void k_gemm2(const unsigned short* __restrict__ M1,
      const float* __restrict__ W2, const float* __restrict__ b2,
      float* __restrict__ out){
  __shared__ __align__(16) unsigned short WT[128][136];  // WT[n][k]
  __shared__ float bsh[128];
  __shared__ float colpart[8][128];
  const int b=blockIdx.x, tid=threadIdx.x;
  for (int idx=tid; idx<128*128; idx+=512){
    const int k=idx>>7, n=idx&127;
    WT[n][k]=f2bf(W2[idx]);
  }
  if (tid<128) bsh[tid]=b2[tid];
  __syncthreads();
  const int wave=tid>>6, lane=tid&63, l16=lane&15, quad=lane>>4;
  float p[8];
  #pragma unroll
  for (int i=0;i<8;i++) p[i]=0.f;
  for (int chunk=0; chunk<2; ++chunk){
    const int rowbase = b*NPG + wave*64 + chunk*32;
    f32x4 acc[2][8];
    #pragma unroll
    for (int rt=0;rt<2;rt++)
      #pragma unroll
      for (int ct=0;ct<8;ct++) acc[rt][ct]=(f32x4){0.f,0.f,0.f,0.f};
    #pragma unroll
    for (int ks=0;ks<4;ks++){
      s16x8 a[2], bf[8];
      #pragma unroll
      for (int rt=0;rt<2;rt++){
        const unsigned short* ap = M1 + (size_t)(rowbase+rt*16+l16)*128 + ks*32 + quad*8;
        a[rt]=__builtin_bit_cast(s16x8, *(const uint4*)ap);
      }
      #pragma unroll
      for (int ct=0;ct<8;ct++)
        bf[ct]=__builtin_bit_cast(s16x8, *(const uint4*)&WT[ct*16+l16][ks*32+quad*8]);
      #pragma unroll
      for (int rt=0;rt<2;rt++)
        #pragma unroll
        for (int ct=0;ct<8;ct++)
          acc[rt][ct]=__builtin_amdgcn_mfma_f32_16x16x32_bf16(a[rt],bf[ct],acc[rt][ct],0,0,0);
    }
    #pragma unroll
    for (int rt=0;rt<2;rt++)
      #pragma unroll
      for (int ct=0;ct<8;ct++)
        #pragma unroll
        for (int r=0;r<4;r++){
          const int col=ct*16+l16;
          p[ct] += fmaxf(acc[rt][ct][r]+bsh[col],0.f);
        }
  }
  #pragma unroll
  for (int ct=0;ct<8;ct++){
    p[ct] += __shfl_xor(p[ct],16);
    p[ct] += __shfl_xor(p[ct],32);
  }
  if (quad==0){
    #pragma unroll
    for (int ct=0;ct<8;ct++) colpart[wave][ct*16+l16]=p[ct];
  }
  __syncthreads();
  if (tid<128){
    float s=0.f;
    #pragma unroll
    for (int w=0;w<8;w++) s+=colpart[w][tid];
    out[b*128+tid]=s*(1.f/512.f);
  }
}

extern "C" void kernel_launch(void* const* d_in, const int* in_sizes, int n_in,
                              void* d_out, int out_size, void* d_ws, size_t ws_size,
                              hipStream_t stream){
  const int* node_feat = (const int*)d_in[0];
  const int* src = (const int*)d_in[1];
  const int* dst = (const int*)d_in[2];
  const float* emb = (const float*)d_in[3];
  const float* W1  = (const float*)d_in[4];
  const float* b1  = (const float*)d_in[5];
  const float* W2  = (const float*)d_in[6];
  const float* b2  = (const float*)d_in[7];

  char* ws = (char*)d_ws;
  float* out_isqrt        = (float*)(ws);                          // 524288 B
  int* start_g            = (int*)(ws + 524288);                   // 525312 B
  unsigned short* sorted_g= (unsigned short*)(ws + 1049600);       // 4194304 B
  unsigned short* EW1T    = (unsigned short*)(ws + 5243904);       // 16384 B
  unsigned short* h1T     = (unsigned short*)(ws + 5260288);       // 33554432 B
  unsigned short* M1      = (unsigned short*)(ws + 38814720);      // 33554432 B

  (void)hipFuncSetAttribute(reinterpret_cast<const void*>(&k_agg1),
        hipFuncAttributeMaxDynamicSharedMemorySize, A1_LDS);
  (void)hipFuncSetAttribute(reinterpret_cast<const void*>(&k_agg2),
        hipFuncAttributeMaxDynamicSharedMemorySize, A2_LDS);

  k_csr<<<GRAPHS+16,512,0,stream>>>(src,dst,node_feat,emb,W1,
        sorted_g,start_g,out_isqrt,EW1T);
  k_agg1<<<GRAPHS*2,512,A1_LDS,stream>>>(sorted_g,start_g,EW1T,out_isqrt,b1,h1T);
  k_agg2<<<GRAPHS*8,512,A2_LDS,stream>>>(sorted_g,start_g,h1T,M1);
  k_gemm2<<<GRAPHS,512,0,stream>>>(M1,W2,b2,(float*)d_out);
}

// Round 13
// 151.809 us; speedup vs baseline: 1.6478x; 1.6478x over previous
//
#include <hip/hip_runtime.h>
#include <stdint.h>

#define GRAPHS 256
#define NPG    512
#define EPG    8192
#define NTOT   (GRAPHS*NPG)

typedef __attribute__((ext_vector_type(8))) short s16x8;
typedef __attribute__((ext_vector_type(4))) float f32x4;

__device__ __forceinline__ float bf2f(unsigned short u){
  union { unsigned int i; float f; } c; c.i = ((unsigned int)u)<<16; return c.f;
}
__device__ __forceinline__ unsigned short f2bf(float f){
  union { float f; unsigned int i; } c; c.f = f;
  unsigned int r = c.i + 0x7fffu + ((c.i>>16)&1u);   // RNE
  return (unsigned short)(r>>16);
}

// ---------- CSR build + out_isqrt (blocks 0..255) ; EW1T prep (256..271) ----
__global__ __launch_bounds__(512) void k_csr(const int* __restrict__ src,
      const int* __restrict__ dst, const int* __restrict__ ntype,
      const float* __restrict__ emb, const float* __restrict__ W1,
      unsigned short* __restrict__ sorted_g, int* __restrict__ start_g,
      float* __restrict__ out_isqrt, unsigned short* __restrict__ EW1T){
  __shared__ int hist[NPG], cursor[NPG], co[NPG], cs[NPG+1];
  __shared__ unsigned short ntype_sh[NPG];
  __shared__ unsigned short sorted[EPG];
  const int tid=threadIdx.x;
  if (blockIdx.x >= GRAPHS){                     // fused EW1T = (emb@W1)^T
    const int gid = (blockIdx.x-GRAPHS)*512 + tid;   // 16 blocks * 512 = 8192
    const int t = gid>>7, c = gid&127;
    float acc=0.f;
    #pragma unroll 4
    for (int k=0;k<128;k++) acc += emb[t*128+k]*W1[k*128+c];
    EW1T[c*64+t]=f2bf(acc);
    return;
  }
  const int b=blockIdx.x, eb=b*EPG, nb=b*NPG;
  for (int v=tid; v<NPG; v+=512){
    hist[v]=0; co[v]=0; ntype_sh[v]=(unsigned short)ntype[nb+v];
  }
  __syncthreads();
  for (int i=tid;i<EPG;i+=512){
    atomicAdd(&hist[dst[eb+i]&(NPG-1)],1);
    atomicAdd(&co[src[eb+i]&(NPG-1)],1);
  }
  __syncthreads();
  if (tid<64){
    int carry=0;
    #pragma unroll
    for (int c=0;c<8;c++){
      int sc=hist[64*c+tid];
      #pragma unroll
      for (int off=1;off<64;off<<=1){ int y=__shfl_up(sc,off); if (tid>=off) sc+=y; }
      cs[64*c+tid+1]=carry+sc;
      carry+=__shfl(sc,63);
    }
    if (tid==0) cs[0]=0;
  }
  __syncthreads();
  for (int v=tid;v<NPG;v+=512) cursor[v]=cs[v];
  __syncthreads();
  for (int i=tid;i<EPG;i+=512){
    const int s=src[eb+i]&(NPG-1), d=dst[eb+i]&(NPG-1);
    const int pos=atomicAdd(&cursor[d],1);
    sorted[pos]=(unsigned short)((ntype_sh[s]<<9)|s);
  }
  __syncthreads();
  for (int i=tid;i<EPG/2;i+=512)
    ((unsigned int*)(sorted_g+(size_t)eb))[i] = ((const unsigned int*)sorted)[i];
  for (int v=tid;v<=NPG;v+=512) start_g[b*(NPG+1)+v]=cs[v];
  for (int v=tid;v<NPG;v+=512){
    int a=co[v]; if(a<1)a=1;
    out_isqrt[nb+v]=rsqrtf((float)a);
  }
}

// ---------- layer-1: S-histogram + MFMA(S_hi/lo @ EW1) ----------------------
// block = (graph, half: 256 dst rows), 512 thr (R7/R10-proven config).
// Output h1 stored in MFMA-B-FRAGMENT order for agg2's coalesced loads:
//   h1F ushort offset = (((b*16+ks)*8 + ct)*64 + quad'*16 + l16)*8 + j
//   where ks=dst>>5, quad'=(dst>>3)&3, j=dst&7, ct=col>>4, l16=col&15.
// value = relu(agg*in_isqrt + b1) * out_isqrt  (bf16)
#define A1_LDS 73232   // S f32[256][68] | wsc[512] | sstart[257] | bsh[128]
__global__ __launch_bounds__(512) void k_agg1(
      const unsigned short* __restrict__ sorted_g, const int* __restrict__ start_g,
      const unsigned short* __restrict__ EW1T, const float* __restrict__ out_isqrt,
      const float* __restrict__ b1, unsigned short* __restrict__ h1F){
  extern __shared__ char smem[];
  float* S      = (float*)(smem);               // [256][68]
  float* wsc    = (float*)(smem + 69632);       // [512]
  int*   sstart = (int*)  (smem + 71680);       // [257]
  float* bsh    = (float*)(smem + 72720);       // [128]
  const int bid=blockIdx.x, b=bid>>1, half=bid&1;
  const int v0=half*256, nb=b*NPG, tid=threadIdx.x;
  for (int i=tid; i<(256*68)/4; i+=512) ((f32x4*)S)[i]=(f32x4){0.f,0.f,0.f,0.f};
  for (int i=tid; i<NPG; i+=512) wsc[i]=out_isqrt[nb+i];
  for (int i=tid; i<257; i+=512) sstart[i]=start_g[b*(NPG+1)+v0+i];
  if (tid<128) bsh[tid]=b1[tid];
  __syncthreads();
  if (tid<256){                                 // thread-per-dst scatter
    const int beg=sstart[tid], end=sstart[tid+1];
    float* Sd = S + tid*68;
    const unsigned short* sg = sorted_g + (size_t)b*EPG;
    for (int i=beg;i<end;++i){
      const int ent = sg[i];
      Sd[ent>>9] += wsc[ent&511];
    }
  }
  __syncthreads();
  const int wave=tid>>6, lane=tid&63, l16=lane&15, quad=lane>>4;
  f32x4 acc[2][8];
  #pragma unroll
  for (int rt=0;rt<2;rt++)
    #pragma unroll
    for (int nt=0;nt<8;nt++) acc[rt][nt]=(f32x4){0.f,0.f,0.f,0.f};
  #pragma unroll
  for (int ks=0; ks<4; ++ks){                   // ks 0,1 = hi; 2,3 = lo
    const int kc = (ks&1)*32 + quad*8;
    s16x8 a[2];
    #pragma unroll
    for (int rt=0;rt<2;rt++){
      const int m = (wave*2+rt)*16 + l16;
      const float* sp = &S[m*68 + kc];
      f32x4 va = *(const f32x4*)sp;
      f32x4 vb = *(const f32x4*)(sp+4);
      union { s16x8 v; unsigned short u[8]; } pk;
      #pragma unroll
      for (int j=0;j<8;j++){
        const float f = (j<4)? va[j] : vb[j-4];
        const unsigned short hi = f2bf(f);
        pk.u[j] = (ks<2) ? hi : f2bf(f - bf2f(hi));
      }
      a[rt]=pk.v;
    }
    #pragma unroll
    for (int nt=0;nt<8;nt++){
      s16x8 bfr=__builtin_bit_cast(s16x8,
          *(const uint4*)(EW1T + (size_t)(nt*16+l16)*64 + kc));
      #pragma unroll
      for (int rt=0;rt<2;rt++)
        acc[rt][nt]=__builtin_amdgcn_mfma_f32_16x16x32_bf16(a[rt],bfr,acc[rt][nt],0,0,0);
    }
  }
  #pragma unroll
  for (int rt=0;rt<2;rt++){
    const int W = wave*2+rt;                    // m-tile in [0,16) within half
    const int mloc = W*16 + quad*4;
    float isq[4], os[4];
    #pragma unroll
    for (int r=0;r<4;r++){
      int d = sstart[mloc+r+1]-sstart[mloc+r]; if (d<1) d=1;
      isq[r]=rsqrtf((float)d);
      os[r]=wsc[v0+mloc+r];
    }
    // fragment-order address components (derived from dst = v0+mloc+r):
    const int ks2 = half*8 + (W>>1);
    const int q2  = ((W&1)<<1) | (quad>>1);
    const int j0  = (quad&1)*4;
    #pragma unroll
    for (int nt=0;nt<8;nt++){
      const int col = nt*16+l16;
      const float bb = bsh[col];
      ushort4 st;
      float v;
      v = fmaxf(acc[rt][nt][0]*isq[0]+bb,0.f)*os[0]; st.x=f2bf(v);
      v = fmaxf(acc[rt][nt][1]*isq[1]+bb,0.f)*os[1]; st.y=f2bf(v);
      v = fmaxf(acc[rt][nt][2]*isq[2]+bb,0.f)*os[2]; st.z=f2bf(v);
      v = fmaxf(acc[rt][nt][3]*isq[3]+bb,0.f)*os[3]; st.w=f2bf(v);
      const size_t off = ((((size_t)b*16 + ks2)*8 + nt)*64 + q2*16 + l16)*8 + j0;
      *(ushort4*)(h1F + off) = st;
    }
  }
}

// ---------- layer-2: A(u8 counts) @ h1F via MFMA -> M1 ----------------------
// block = (graph, 128-dst tile), 512 thr, 67 KB LDS -> 2 blocks/CU (R10 cfg).
// B-fragments now read COALESCED from fragment-ordered h1F (1 KB/wave-load,
// sequential lines) -- attacks the L1 request-rate bound seen in R7..R12.
#define A2_LDS 67080   // A u8[128][520] | sstart[129]
__global__ __launch_bounds__(512) void k_agg2(
      const unsigned short* __restrict__ sorted_g, const int* __restrict__ start_g,
      const unsigned short* __restrict__ h1F, unsigned short* __restrict__ M1){
  extern __shared__ char smem[];
  unsigned char* A = (unsigned char*)smem;      // [128][520]
  unsigned int* A32 = (unsigned int*)smem;
  int* sstart = (int*)(smem + 66560);           // [129]
  const int bid=blockIdx.x;
  const int b  = ((bid>>5)<<3) | (bid&7);       // graph (XCD swizzle)
  const int dt = (bid>>3)&3;                    // dst tile
  const int v0=dt*128, nb=b*NPG, tid=threadIdx.x;
  for (int i=tid; i<66560/16; i+=512) ((uint4*)smem)[i]=(uint4){0u,0u,0u,0u};
  for (int i=tid; i<129; i+=512) sstart[i]=start_g[b*(NPG+1)+v0+i];
  __syncthreads();
  {                                             // parallel count scatter: 4 thr/dst
    const int d = tid>>2, q = tid&3;
    const int beg=sstart[d], end=sstart[d+1], len=end-beg;
    const int qb = beg + ((len*q)>>2), qe = beg + ((len*(q+1))>>2);
    const unsigned short* sg = sorted_g + (size_t)b*EPG;
    const int rowbase = d*130;
    for (int i=qb;i<qe;++i){
      const int s = sg[i]&511;
      atomicAdd(&A32[rowbase + (s>>2)], 1u<<((s&3)*8));
    }
  }
  __syncthreads();
  const int wave=tid>>6, lane=tid&63, l16=lane&15, quad=lane>>4;
  const int mg=wave>>1, ng=wave&1;              // 8 m-tiles x 8 n-tiles total
  f32x4 acc[2][4];
  #pragma unroll
  for (int rt=0;rt<2;rt++)
    #pragma unroll
    for (int ct=0;ct<4;ct++) acc[rt][ct]=(f32x4){0.f,0.f,0.f,0.f};

  const uint4* bp[4];                           // coalesced fragment pointers
  #pragma unroll
  for (int ct=0;ct<4;ct++)
    bp[ct] = (const uint4*)h1F + (((size_t)b*16)*8 + (ng*4+ct))*64 + lane;
  const unsigned char* Ab[2];
  #pragma unroll
  for (int rt=0;rt<2;rt++)
    Ab[rt] = A + ((mg*2+rt)*16 + l16)*520 + quad*8;

  #pragma unroll 2
  for (int ks=0; ks<16; ++ks){
    uint4 bq[4];
    #pragma unroll
    for (int ct=0;ct<4;ct++) bq[ct] = bp[ct][(size_t)ks*512];  // ks stride: 8ct*64
    s16x8 afr[2];
    #pragma unroll
    for (int rt=0;rt<2;rt++){
      const uint2 aw = *(const uint2*)(Ab[rt] + ks*32);
      union { s16x8 v; unsigned short u[8]; } pk;
      #pragma unroll
      for (int j=0;j<4;j++){
        const float f0 = (float)((aw.x>>(8*j))&0xffu);   // exact small ints
        const float f1 = (float)((aw.y>>(8*j))&0xffu);
        pk.u[j]   = (unsigned short)(__builtin_bit_cast(unsigned int, f0)>>16);
        pk.u[j+4] = (unsigned short)(__builtin_bit_cast(unsigned int, f1)>>16);
      }
      afr[rt]=pk.v;
    }
    #pragma unroll
    for (int rt=0;rt<2;rt++)
      #pragma unroll
      for (int ct=0;ct<4;ct++)
        acc[rt][ct]=__builtin_amdgcn_mfma_f32_16x16x32_bf16(afr[rt],
            __builtin_bit_cast(s16x8, bq[ct]), acc[rt][ct],0,0,0);
  }
  #pragma unroll
  for (int rt=0;rt<2;rt++){
    const int mloc=(mg*2+rt)*16 + quad*4;
    float isq[4];
    #pragma unroll
    for (int r=0;r<4;r++){
      int d=sstart[mloc+r+1]-sstart[mloc+r]; if (d<1) d=1;
      isq[r]=rsqrtf((float)d);
    }
    #pragma unroll
    for (int ct=0;ct<4;ct++){
      const int col=ng*64 + ct*16 + l16;
      #pragma unroll
      for (int r=0;r<4;r++)
        M1[(size_t)(nb+v0+mloc+r)*128 + col] = f2bf(acc[rt][ct][r]*isq[r]);
    }
  }
}

// ---------- final GEMM: relu(M1 @ W2 + b2), fused per-graph mean -> out -----
__global__ __launch_bounds__(512) void k_gemm2(const unsigned short* __restrict__ M1,
      const float* __restrict__ W2, const float* __restrict__ b2,
      float* __restrict__ out){
  __shared__ __align__(16) unsigned short WT[128][136];  // WT[n][k]
  __shared__ float bsh[128];
  __shared__ float colpart[8][128];
  const int b=blockIdx.x, tid=threadIdx.x;
  for (int idx=tid; idx<128*128; idx+=512){
    const int k=idx>>7, n=idx&127;
    WT[n][k]=f2bf(W2[idx]);
  }
  if (tid<128) bsh[tid]=b2[tid];
  __syncthreads();
  const int wave=tid>>6, lane=tid&63, l16=lane&15, quad=lane>>4;
  float p[8];
  #pragma unroll
  for (int i=0;i<8;i++) p[i]=0.f;
  for (int chunk=0; chunk<2; ++chunk){
    const int rowbase = b*NPG + wave*64 + chunk*32;
    f32x4 acc[2][8];
    #pragma unroll
    for (int rt=0;rt<2;rt++)
      #pragma unroll
      for (int ct=0;ct<8;ct++) acc[rt][ct]=(f32x4){0.f,0.f,0.f,0.f};
    #pragma unroll
    for (int ks=0;ks<4;ks++){
      s16x8 a[2], bf[8];
      #pragma unroll
      for (int rt=0;rt<2;rt++){
        const unsigned short* ap = M1 + (size_t)(rowbase+rt*16+l16)*128 + ks*32 + quad*8;
        a[rt]=__builtin_bit_cast(s16x8, *(const uint4*)ap);
      }
      #pragma unroll
      for (int ct=0;ct<8;ct++)
        bf[ct]=__builtin_bit_cast(s16x8, *(const uint4*)&WT[ct*16+l16][ks*32+quad*8]);
      #pragma unroll
      for (int rt=0;rt<2;rt++)
        #pragma unroll
        for (int ct=0;ct<8;ct++)
          acc[rt][ct]=__builtin_amdgcn_mfma_f32_16x16x32_bf16(a[rt],bf[ct],acc[rt][ct],0,0,0);
    }
    #pragma unroll
    for (int rt=0;rt<2;rt++)
      #pragma unroll
      for (int ct=0;ct<8;ct++)
        #pragma unroll
        for (int r=0;r<4;r++){
          const int col=ct*16+l16;
          p[ct] += fmaxf(acc[rt][ct][r]+bsh[col],0.f);
        }
  }
  #pragma unroll
  for (int ct=0;ct<8;ct++){
    p[ct] += __shfl_xor(p[ct],16);
    p[ct] += __shfl_xor(p[ct],32);
  }
  if (quad==0){
    #pragma unroll
    for (int ct=0;ct<8;ct++) colpart[wave][ct*16+l16]=p[ct];
  }
  __syncthreads();
  if (tid<128){
    float s=0.f;
    #pragma unroll
    for (int w=0;w<8;w++) s+=colpart[w][tid];
    out[b*128+tid]=s*(1.f/512.f);
  }
}

extern "C" void kernel_launch(void* const* d_in, const int* in_sizes, int n_in,
                              void* d_out, int out_size, void* d_ws, size_t ws_size,
                              hipStream_t stream){
  const int* node_feat = (const int*)d_in[0];
  const int* src = (const int*)d_in[1];
  const int* dst = (const int*)d_in[2];
  const float* emb = (const float*)d_in[3];
  const float* W1  = (const float*)d_in[4];
  const float* b1  = (const float*)d_in[5];
  const float* W2  = (const float*)d_in[6];
  const float* b2  = (const float*)d_in[7];

  char* ws = (char*)d_ws;
  float* out_isqrt        = (float*)(ws);                          // 524288 B
  int* start_g            = (int*)(ws + 524288);                   // 525312 B
  unsigned short* sorted_g= (unsigned short*)(ws + 1049600);       // 4194304 B
  unsigned short* EW1T    = (unsigned short*)(ws + 5243904);       // 16384 B
  unsigned short* h1F     = (unsigned short*)(ws + 5260288);       // 33554432 B
  unsigned short* M1      = (unsigned short*)(ws + 38814720);      // 33554432 B

  (void)hipFuncSetAttribute(reinterpret_cast<const void*>(&k_agg1),
        hipFuncAttributeMaxDynamicSharedMemorySize, A1_LDS);
  (void)hipFuncSetAttribute(reinterpret_cast<const void*>(&k_agg2),
        hipFuncAttributeMaxDynamicSharedMemorySize, A2_LDS);

  k_csr<<<GRAPHS+16,512,0,stream>>>(src,dst,node_feat,emb,W1,
        sorted_g,start_g,out_isqrt,EW1T);
  k_agg1<<<GRAPHS*2,512,A1_LDS,stream>>>(sorted_g,start_g,EW1T,out_isqrt,b1,h1F);
  k_agg2<<<GRAPHS*4,512,A2_LDS,stream>>>(sorted_g,start_g,h1F,M1);
  k_gemm2<<<GRAPHS,512,0,stream>>>(M1,W2,b2,(float*)d_out);
}

// Round 14
// 149.976 us; speedup vs baseline: 1.6680x; 1.0122x over previous
//
#include <hip/hip_runtime.h>
#include <stdint.h>

#define GRAPHS 256
#define NPG    512
#define EPG    8192
#define NTOT   (GRAPHS*NPG)

typedef __attribute__((ext_vector_type(8))) short s16x8;
typedef __attribute__((ext_vector_type(4))) float f32x4;

__device__ __forceinline__ float bf2f(unsigned short u){
  union { unsigned int i; float f; } c; c.i = ((unsigned int)u)<<16; return c.f;
}
__device__ __forceinline__ unsigned short f2bf(float f){
  union { float f; unsigned int i; } c; c.f = f;
  unsigned int r = c.i + 0x7fffu + ((c.i>>16)&1u);   // RNE
  return (unsigned short)(r>>16);
}

// ---------- CSR build + out_isqrt (blocks 0..255) ; EW1T prep (256..271) ----
// int4 edge loads held in registers across histogram+scatter (one read, not two)
__global__ __launch_bounds__(512) void k_csr(const int* __restrict__ src,
      const int* __restrict__ dst, const int* __restrict__ ntype,
      const float* __restrict__ emb, const float* __restrict__ W1,
      unsigned short* __restrict__ sorted_g, int* __restrict__ start_g,
      float* __restrict__ out_isqrt, unsigned short* __restrict__ EW1T){
  __shared__ int hist[NPG], cursor[NPG], co[NPG], cs[NPG+1];
  __shared__ unsigned short ntype_sh[NPG];
  __shared__ unsigned short sorted[EPG];
  const int tid=threadIdx.x;
  if (blockIdx.x >= GRAPHS){                     // fused EW1T = (emb@W1)^T
    const int gid = (blockIdx.x-GRAPHS)*512 + tid;   // 16 blocks * 512 = 8192
    const int t = gid>>7, c = gid&127;
    float acc=0.f;
    #pragma unroll 4
    for (int k=0;k<128;k++) acc += emb[t*128+k]*W1[k*128+c];
    EW1T[c*64+t]=f2bf(acc);
    return;
  }
  const int b=blockIdx.x, eb=b*EPG, nb=b*NPG;
  hist[tid]=0; co[tid]=0; ntype_sh[tid]=(unsigned short)ntype[nb+tid];
  __syncthreads();
  int4 d4[4], s4[4];
  {
    const int4* dv = (const int4*)(dst+eb);
    const int4* sv = (const int4*)(src+eb);
    #pragma unroll
    for (int j=0;j<4;j++){
      d4[j]=dv[tid + j*512];
      s4[j]=sv[tid + j*512];
      atomicAdd(&hist[d4[j].x&(NPG-1)],1); atomicAdd(&hist[d4[j].y&(NPG-1)],1);
      atomicAdd(&hist[d4[j].z&(NPG-1)],1); atomicAdd(&hist[d4[j].w&(NPG-1)],1);
      atomicAdd(&co[s4[j].x&(NPG-1)],1);   atomicAdd(&co[s4[j].y&(NPG-1)],1);
      atomicAdd(&co[s4[j].z&(NPG-1)],1);   atomicAdd(&co[s4[j].w&(NPG-1)],1);
    }
  }
  __syncthreads();
  if (tid<64){
    int carry=0;
    #pragma unroll
    for (int c=0;c<8;c++){
      int sc=hist[64*c+tid];
      #pragma unroll
      for (int off=1;off<64;off<<=1){ int y=__shfl_up(sc,off); if (tid>=off) sc+=y; }
      cs[64*c+tid+1]=carry+sc;
      carry+=__shfl(sc,63);
    }
    if (tid==0) cs[0]=0;
  }
  __syncthreads();
  cursor[tid]=cs[tid];
  __syncthreads();
  #pragma unroll
  for (int j=0;j<4;j++){
    int dl, s, pos;
    dl=d4[j].x&(NPG-1); s=s4[j].x&(NPG-1);
    pos=atomicAdd(&cursor[dl],1); sorted[pos]=(unsigned short)((ntype_sh[s]<<9)|s);
    dl=d4[j].y&(NPG-1); s=s4[j].y&(NPG-1);
    pos=atomicAdd(&cursor[dl],1); sorted[pos]=(unsigned short)((ntype_sh[s]<<9)|s);
    dl=d4[j].z&(NPG-1); s=s4[j].z&(NPG-1);
    pos=atomicAdd(&cursor[dl],1); sorted[pos]=(unsigned short)((ntype_sh[s]<<9)|s);
    dl=d4[j].w&(NPG-1); s=s4[j].w&(NPG-1);
    pos=atomicAdd(&cursor[dl],1); sorted[pos]=(unsigned short)((ntype_sh[s]<<9)|s);
  }
  __syncthreads();
  for (int i=tid;i<EPG/2;i+=512)
    ((unsigned int*)(sorted_g+(size_t)eb))[i] = ((const unsigned int*)sorted)[i];
  if (tid==0) start_g[b*(NPG+1)+NPG]=cs[NPG];
  start_g[b*(NPG+1)+tid]=cs[tid];
  {
    int a=co[tid]; if(a<1)a=1;
    out_isqrt[nb+tid]=rsqrtf((float)a);
  }
}

// ---------- layer-1: S-histogram + MFMA(S_hi/lo @ EW1) ----------------------
// block = (graph, half: 256 dst rows), 512 thr. Output h1 in MFMA-B-fragment
// order (R13 win): offset = (((b*16+ks)*8+ct)*64 + q2*16 + l16)*8 + j.
// value = relu(agg*in_isqrt + b1) * out_isqrt  (bf16)
#define A1_LDS 73232   // S f32[256][68] | wsc[512] | sstart[257] | bsh[128]
__global__ __launch_bounds__(512) void k_agg1(
      const unsigned short* __restrict__ sorted_g, const int* __restrict__ start_g,
      const unsigned short* __restrict__ EW1T, const float* __restrict__ out_isqrt,
      const float* __restrict__ b1, unsigned short* __restrict__ h1F){
  extern __shared__ char smem[];
  float* S      = (float*)(smem);               // [256][68]
  float* wsc    = (float*)(smem + 69632);       // [512]
  int*   sstart = (int*)  (smem + 71680);       // [257]
  float* bsh    = (float*)(smem + 72720);       // [128]
  const int bid=blockIdx.x, b=bid>>1, half=bid&1;
  const int v0=half*256, nb=b*NPG, tid=threadIdx.x;
  for (int i=tid; i<(256*68)/4; i+=512) ((f32x4*)S)[i]=(f32x4){0.f,0.f,0.f,0.f};
  for (int i=tid; i<NPG; i+=512) wsc[i]=out_isqrt[nb+i];
  for (int i=tid; i<257; i+=512) sstart[i]=start_g[b*(NPG+1)+v0+i];
  if (tid<128) bsh[tid]=b1[tid];
  __syncthreads();
  if (tid<256){                                 // thread-per-dst scatter
    const int beg=sstart[tid], end=sstart[tid+1];
    float* Sd = S + tid*68;
    const unsigned short* sg = sorted_g + (size_t)b*EPG;
    for (int i=beg;i<end;++i){
      const int ent = sg[i];
      Sd[ent>>9] += wsc[ent&511];
    }
  }
  __syncthreads();
  const int wave=tid>>6, lane=tid&63, l16=lane&15, quad=lane>>4;
  f32x4 acc[2][8];
  #pragma unroll
  for (int rt=0;rt<2;rt++)
    #pragma unroll
    for (int nt=0;nt<8;nt++) acc[rt][nt]=(f32x4){0.f,0.f,0.f,0.f};
  #pragma unroll
  for (int ks=0; ks<4; ++ks){                   // ks 0,1 = hi; 2,3 = lo
    const int kc = (ks&1)*32 + quad*8;
    s16x8 a[2];
    #pragma unroll
    for (int rt=0;rt<2;rt++){
      const int m = (wave*2+rt)*16 + l16;
      const float* sp = &S[m*68 + kc];
      f32x4 va = *(const f32x4*)sp;
      f32x4 vb = *(const f32x4*)(sp+4);
      union { s16x8 v; unsigned short u[8]; } pk;
      #pragma unroll
      for (int j=0;j<8;j++){
        const float f = (j<4)? va[j] : vb[j-4];
        const unsigned short hi = f2bf(f);
        pk.u[j] = (ks<2) ? hi : f2bf(f - bf2f(hi));
      }
      a[rt]=pk.v;
    }
    #pragma unroll
    for (int nt=0;nt<8;nt++){
      s16x8 bfr=__builtin_bit_cast(s16x8,
          *(const uint4*)(EW1T + (size_t)(nt*16+l16)*64 + kc));
      #pragma unroll
      for (int rt=0;rt<2;rt++)
        acc[rt][nt]=__builtin_amdgcn_mfma_f32_16x16x32_bf16(a[rt],bfr,acc[rt][nt],0,0,0);
    }
  }
  #pragma unroll
  for (int rt=0;rt<2;rt++){
    const int W = wave*2+rt;                    // m-tile in [0,16) within half
    const int mloc = W*16 + quad*4;
    float isq[4], os[4];
    #pragma unroll
    for (int r=0;r<4;r++){
      int d = sstart[mloc+r+1]-sstart[mloc+r]; if (d<1) d=1;
      isq[r]=rsqrtf((float)d);
      os[r]=wsc[v0+mloc+r];
    }
    const int ks2 = half*8 + (W>>1);
    const int q2  = ((W&1)<<1) | (quad>>1);
    const int j0  = (quad&1)*4;
    #pragma unroll
    for (int nt=0;nt<8;nt++){
      const int col = nt*16+l16;
      const float bb = bsh[col];
      ushort4 st;
      float v;
      v = fmaxf(acc[rt][nt][0]*isq[0]+bb,0.f)*os[0]; st.x=f2bf(v);
      v = fmaxf(acc[rt][nt][1]*isq[1]+bb,0.f)*os[1]; st.y=f2bf(v);
      v = fmaxf(acc[rt][nt][2]*isq[2]+bb,0.f)*os[2]; st.z=f2bf(v);
      v = fmaxf(acc[rt][nt][3]*isq[3]+bb,0.f)*os[3]; st.w=f2bf(v);
      const size_t off = ((((size_t)b*16 + ks2)*8 + nt)*64 + q2*16 + l16)*8 + j0;
      *(ushort4*)(h1F + off) = st;
    }
  }
}

// ---------- layer-2: A(u8 counts) @ h1F via MFMA -> M1F ---------------------
// block = (graph, 128-dst tile), 512 thr, 67 KB LDS -> 2 blocks/CU.
// B-loads coalesced from h1F (R13); M1 now STORED in gemm2-A-fragment order:
//   M1F ushort offset = (((b*32+M)*4+ks)*64 + quad2*16 + l16_2)*8 + j
//   with M=dt*8+mg*2+rt, ks=ng*2+(ct>>1), quad2=((ct&1)<<1)|(l16>>3),
//   j=l16&7, l16_2=quad*4+r  -> 1KB-window stores, coalesced gemm2 reads.
#define A2_LDS 67080   // A u8[128][520] | sstart[129]
__global__ __launch_bounds__(512) void k_agg2(
      const unsigned short* __restrict__ sorted_g, const int* __restrict__ start_g,
      const unsigned short* __restrict__ h1F, unsigned short* __restrict__ M1F){
  extern __shared__ char smem[];
  unsigned char* A = (unsigned char*)smem;      // [128][520]
  unsigned int* A32 = (unsigned int*)smem;
  int* sstart = (int*)(smem + 66560);           // [129]
  const int bid=blockIdx.x;
  const int b  = ((bid>>5)<<3) | (bid&7);       // graph (XCD swizzle)
  const int dt = (bid>>3)&3;                    // dst tile
  const int v0=dt*128, tid=threadIdx.x;
  for (int i=tid; i<66560/16; i+=512) ((uint4*)smem)[i]=(uint4){0u,0u,0u,0u};
  for (int i=tid; i<129; i+=512) sstart[i]=start_g[b*(NPG+1)+v0+i];
  __syncthreads();
  {                                             // parallel count scatter: 4 thr/dst
    const int d = tid>>2, q = tid&3;
    const int beg=sstart[d], end=sstart[d+1], len=end-beg;
    const int qb = beg + ((len*q)>>2), qe = beg + ((len*(q+1))>>2);
    const unsigned short* sg = sorted_g + (size_t)b*EPG;
    const int rowbase = d*130;
    for (int i=qb;i<qe;++i){
      const int s = sg[i]&511;
      atomicAdd(&A32[rowbase + (s>>2)], 1u<<((s&3)*8));
    }
  }
  __syncthreads();
  const int wave=tid>>6, lane=tid&63, l16=lane&15, quad=lane>>4;
  const int mg=wave>>1, ng=wave&1;              // 8 m-tiles x 8 n-tiles total
  f32x4 acc[2][4];
  #pragma unroll
  for (int rt=0;rt<2;rt++)
    #pragma unroll
    for (int ct=0;ct<4;ct++) acc[rt][ct]=(f32x4){0.f,0.f,0.f,0.f};

  const uint4* bp[4];                           // coalesced fragment pointers
  #pragma unroll
  for (int ct=0;ct<4;ct++)
    bp[ct] = (const uint4*)h1F + (((size_t)b*16)*8 + (ng*4+ct))*64 + lane;
  const unsigned char* Ab[2];
  #pragma unroll
  for (int rt=0;rt<2;rt++)
    Ab[rt] = A + ((mg*2+rt)*16 + l16)*520 + quad*8;

  #pragma unroll 2
  for (int ks=0; ks<16; ++ks){
    uint4 bq[4];
    #pragma unroll
    for (int ct=0;ct<4;ct++) bq[ct] = bp[ct][(size_t)ks*512];  // ks stride: 8ct*64
    s16x8 afr[2];
    #pragma unroll
    for (int rt=0;rt<2;rt++){
      const uint2 aw = *(const uint2*)(Ab[rt] + ks*32);
      union { s16x8 v; unsigned short u[8]; } pk;
      #pragma unroll
      for (int j=0;j<4;j++){
        const float f0 = (float)((aw.x>>(8*j))&0xffu);   // exact small ints
        const float f1 = (float)((aw.y>>(8*j))&0xffu);
        pk.u[j]   = (unsigned short)(__builtin_bit_cast(unsigned int, f0)>>16);
        pk.u[j+4] = (unsigned short)(__builtin_bit_cast(unsigned int, f1)>>16);
      }
      afr[rt]=pk.v;
    }
    #pragma unroll
    for (int rt=0;rt<2;rt++)
      #pragma unroll
      for (int ct=0;ct<4;ct++)
        acc[rt][ct]=__builtin_amdgcn_mfma_f32_16x16x32_bf16(afr[rt],
            __builtin_bit_cast(s16x8, bq[ct]), acc[rt][ct],0,0,0);
  }
  #pragma unroll
  for (int rt=0;rt<2;rt++){
    const int mloc=(mg*2+rt)*16 + quad*4;
    const int M = dt*8 + mg*2 + rt;
    float isq[4];
    #pragma unroll
    for (int r=0;r<4;r++){
      int d=sstart[mloc+r+1]-sstart[mloc+r]; if (d<1) d=1;
      isq[r]=rsqrtf((float)d);
    }
    #pragma unroll
    for (int ct=0;ct<4;ct++){
      const int ks2   = ng*2 + (ct>>1);
      const int quad2 = ((ct&1)<<1) | (l16>>3);
      const int j     = l16&7;
      unsigned short* base = M1F
          + ((((size_t)b*32+M)*4+ks2)*64 + quad2*16)*8 + j;
      #pragma unroll
      for (int r=0;r<4;r++)
        base[(size_t)(quad*4+r)*8] = f2bf(acc[rt][ct][r]*isq[r]);
    }
  }
}

// ---------- final GEMM: relu(M1F @ W2 + b2), fused per-graph mean -> out ----
// A-fragments read coalesced from fragment-ordered M1F.
__global__ __launch_bounds__(512) void k_gemm2(const unsigned short* __restrict__ M1F,
      const float* __restrict__ W2, const float* __restrict__ b2,
      float* __restrict__ out){
  __shared__ __align__(16) unsigned short WT[128][136];  // WT[n][k]
  __shared__ float bsh[128];
  __shared__ float colpart[8][128];
  const int b=blockIdx.x, tid=threadIdx.x;
  for (int idx=tid; idx<128*128; idx+=512){
    const int k=idx>>7, n=idx&127;
    WT[n][k]=f2bf(W2[idx]);
  }
  if (tid<128) bsh[tid]=b2[tid];
  __syncthreads();
  const int wave=tid>>6, lane=tid&63, l16=lane&15, quad=lane>>4;
  float p[8];
  #pragma unroll
  for (int i=0;i<8;i++) p[i]=0.f;
  for (int chunk=0; chunk<2; ++chunk){
    f32x4 acc[2][8];
    #pragma unroll
    for (int rt=0;rt<2;rt++)
      #pragma unroll
      for (int ct=0;ct<8;ct++) acc[rt][ct]=(f32x4){0.f,0.f,0.f,0.f};
    #pragma unroll
    for (int ks=0;ks<4;ks++){
      s16x8 a[2], bf[8];
      #pragma unroll
      for (int rt=0;rt<2;rt++){
        const int M = wave*4 + chunk*2 + rt;
        a[rt]=__builtin_bit_cast(s16x8, *(const uint4*)(M1F
            + ((((size_t)b*32+M)*4+ks)*64 + lane)*8));
      }
      #pragma unroll
      for (int ct=0;ct<8;ct++)
        bf[ct]=__builtin_bit_cast(s16x8, *(const uint4*)&WT[ct*16+l16][ks*32+quad*8]);
      #pragma unroll
      for (int rt=0;rt<2;rt++)
        #pragma unroll
        for (int ct=0;ct<8;ct++)
          acc[rt][ct]=__builtin_amdgcn_mfma_f32_16x16x32_bf16(a[rt],bf[ct],acc[rt][ct],0,0,0);
    }
    #pragma unroll
    for (int rt=0;rt<2;rt++)
      #pragma unroll
      for (int ct=0;ct<8;ct++)
        #pragma unroll
        for (int r=0;r<4;r++){
          const int col=ct*16+l16;
          p[ct] += fmaxf(acc[rt][ct][r]+bsh[col],0.f);
        }
  }
  #pragma unroll
  for (int ct=0;ct<8;ct++){
    p[ct] += __shfl_xor(p[ct],16);
    p[ct] += __shfl_xor(p[ct],32);
  }
  if (quad==0){
    #pragma unroll
    for (int ct=0;ct<8;ct++) colpart[wave][ct*16+l16]=p[ct];
  }
  __syncthreads();
  if (tid<128){
    float s=0.f;
    #pragma unroll
    for (int w=0;w<8;w++) s+=colpart[w][tid];
    out[b*128+tid]=s*(1.f/512.f);
  }
}

extern "C" void kernel_launch(void* const* d_in, const int* in_sizes, int n_in,
                              void* d_out, int out_size, void* d_ws, size_t ws_size,
                              hipStream_t stream){
  const int* node_feat = (const int*)d_in[0];
  const int* src = (const int*)d_in[1];
  const int* dst = (const int*)d_in[2];
  const float* emb = (const float*)d_in[3];
  const float* W1  = (const float*)d_in[4];
  const float* b1  = (const float*)d_in[5];
  const float* W2  = (const float*)d_in[6];
  const float* b2  = (const float*)d_in[7];

  char* ws = (char*)d_ws;
  float* out_isqrt        = (float*)(ws);                          // 524288 B
  int* start_g            = (int*)(ws + 524288);                   // 525312 B
  unsigned short* sorted_g= (unsigned short*)(ws + 1049600);       // 4194304 B
  unsigned short* EW1T    = (unsigned short*)(ws + 5243904);       // 16384 B
  unsigned short* h1F     = (unsigned short*)(ws + 5260288);       // 33554432 B
  unsigned short* M1F     = (unsigned short*)(ws + 38814720);      // 33554432 B

  (void)hipFuncSetAttribute(reinterpret_cast<const void*>(&k_agg1),
        hipFuncAttributeMaxDynamicSharedMemorySize, A1_LDS);
  (void)hipFuncSetAttribute(reinterpret_cast<const void*>(&k_agg2),
        hipFuncAttributeMaxDynamicSharedMemorySize, A2_LDS);

  k_csr<<<GRAPHS+16,512,0,stream>>>(src,dst,node_feat,emb,W1,
        sorted_g,start_g,out_isqrt,EW1T);
  k_agg1<<<GRAPHS*2,512,A1_LDS,stream>>>(sorted_g,start_g,EW1T,out_isqrt,b1,h1F);
  k_agg2<<<GRAPHS*4,512,A2_LDS,stream>>>(sorted_g,start_g,h1F,M1F);
  k_gemm2<<<GRAPHS,512,0,stream>>>(M1F,W2,b2,(float*)d_out);
}